// Round 11
// baseline (34.285 us; speedup 1.0000x reference)
//
#include <hip/hip_runtime.h>

#define B_ 4
#define J_ 8160               // 68*120 cells per batch (divisible by 4)
#define NQ_ 2040              // J_/4 quads per batch
#define HF 544
#define WF 960
#define TS 32
#define TXN 30
#define TYN 17
#define NTPB 510              // tiles per batch; grid = 2040 blocks = 8/CU
#define R2COEF 23.0259f       // 2*ln(1e5): exact per-cell cut (d^2 <= R2COEF*var)
#define RMAX2 1474.0f         // 23.0259 * var_max(=64): var-free position pre-test

typedef _Float16 half8 __attribute__((ext_vector_type(8)));
typedef float floatx16 __attribute__((ext_vector_type(16)));

// SINGLE dispatch (R1-R10 fit: ~7us per graph node). One block per 32x32 tile,
// 4 waves; wave w scans 4 cells/lane/iter (8 iters over its 2048-cell slice):
//   - float4 mean loads only (8B/cell) for a fixed-radius position pre-test;
//   - var/conf float4 loads PREDICATED on the quad having a pos-passer
//     (~8% of lanes) -> scan L2 traffic 266 MB -> ~143 MB;
//   - exact refine (d^2 <= 23.03*v, conf>0.1), ballot-compact COMPLETE records
//     (mx,my,1/(2v),cf) into the per-wave LDS queue (R10-validated).
// Drain 16 cells/MFMA via v_mfma_f32_32x32x16_f16 (layout validated R3-R10:
// cell -> same k-slot (half,i) in A and B; C/D row=(r&3)+8*(r>>2)+4*half).
// LDS-reduce 4 partial tiles, store.
__global__ __launch_bounds__(256, 8) void pif_one(const float2* __restrict__ mean,
                                                  const float*  __restrict__ var,
                                                  const float*  __restrict__ conf,
                                                  float* __restrict__ out) {
    __shared__ float4 qbuf[4][256];    // per-wave survivor queues; re-used as red[]
    int wid  = threadIdx.x >> 6;
    int lane = threadIdx.x & 63;
    int tile = blockIdx.x;             // 0..509
    int b    = blockIdx.y;

    int ty = tile / TXN;
    int tx = tile - ty * TXN;

    const float4* mb4 = (const float4*)(mean + (size_t)b * J_);  // [2k]=cells 4k,4k+1
    const float4* vb4 = (const float4*)(var  + (size_t)b * J_);  // [k]=cells 4k..4k+3
    const float4* cb4 = (const float4*)(conf + (size_t)b * J_);

    float4* q = qbuf[wid];
    int qn = 0;

    float x0 = (float)(tx * TS), y0 = (float)(ty * TS);
    float x1 = x0 + 31.f,        y1 = y0 + 31.f;
    int   lx = lane & 31, half = lane >> 5;
    float xf = x0 + (float)lx;
    float yf = y0 + (float)lx;
    const unsigned long long below = (1ull << lane) - 1ull;

    floatx16 acc = {};

    auto drain16 = [&](int base) {     // consumes q[base..base+15], LDS-only
        half8 af, bf;
        #pragma unroll
        for (int i = 0; i < 8; ++i) {
            float4 e = q[base + 8 * half + i];   // uniform per half-wave: broadcast
            float dy = yf - e.y;
            float dx = xf - e.x;
            af[i] = (_Float16)__expf(-dy * dy * e.z);
            bf[i] = (_Float16)(e.w * __expf(-dx * dx * e.z));  // w=0 -> no contribution
        }
        acc = __builtin_amdgcn_mfma_f32_32x32x16_f16(af, bf, acc, 0, 0, 0);
    };

    // clamped-point squared distance to the tile's pixel box
    auto pdist2 = [&](float mx, float my) {
        float dx = mx - fminf(fmaxf(mx, x0), x1);
        float dy = my - fminf(fmaxf(my, y0), y1);
        return dx * dx + dy * dy;
    };

    const int kbase = wid * 512;                 // quad index base of this wave's slice
    for (int s = 0; s < 8; ++s) {
        int  k     = kbase + s * 64 + lane;      // quad = cells 4k..4k+3
        bool valid = k < NQ_;
        int  kc    = valid ? k : 0;

        float4 m01 = mb4[2 * kc];                // means of cells 4k, 4k+1
        float4 m23 = mb4[2 * kc + 1];            // means of cells 4k+2, 4k+3

        float dd0 = pdist2(m01.x, m01.y);
        float dd1 = pdist2(m01.z, m01.w);
        float dd2 = pdist2(m23.x, m23.y);
        float dd3 = pdist2(m23.z, m23.w);
        bool g0 = valid & (dd0 <= RMAX2);        // var-free position pre-test
        bool g1 = valid & (dd1 <= RMAX2);
        bool g2 = valid & (dd2 <= RMAX2);
        bool g3 = valid & (dd3 <= RMAX2);

        float4 vv = make_float4(1.f, 1.f, 1.f, 1.f);
        float4 cc = make_float4(0.f, 0.f, 0.f, 0.f);
        if (g0 | g1 | g2 | g3) {                 // predicated: ~8% of lanes active
            vv = vb4[kc];
            cc = cb4[kc];
        }

        bool p0 = g0 & (cc.x > 0.1f) & (dd0 <= R2COEF * vv.x);
        bool p1 = g1 & (cc.y > 0.1f) & (dd1 <= R2COEF * vv.y);
        bool p2 = g2 & (cc.z > 0.1f) & (dd2 <= R2COEF * vv.z);
        bool p3 = g3 & (cc.w > 0.1f) & (dd3 <= R2COEF * vv.w);

        unsigned long long mk;
        // compact survivor RECORDS; cap 256, drain guard keeps qn+64 <= 255
        mk = __ballot(p0);
        if (p0) q[qn + __popcll(mk & below)] =
            make_float4(m01.x, m01.y, __builtin_amdgcn_rcpf(2.0f * vv.x), cc.x);
        qn += __popcll(mk);
        if (__builtin_expect(qn >= 192, 0)) { while (qn >= 16) { qn -= 16; drain16(qn); } }

        mk = __ballot(p1);
        if (p1) q[qn + __popcll(mk & below)] =
            make_float4(m01.z, m01.w, __builtin_amdgcn_rcpf(2.0f * vv.y), cc.y);
        qn += __popcll(mk);
        if (__builtin_expect(qn >= 192, 0)) { while (qn >= 16) { qn -= 16; drain16(qn); } }

        mk = __ballot(p2);
        if (p2) q[qn + __popcll(mk & below)] =
            make_float4(m23.x, m23.y, __builtin_amdgcn_rcpf(2.0f * vv.z), cc.z);
        qn += __popcll(mk);
        if (__builtin_expect(qn >= 192, 0)) { while (qn >= 16) { qn -= 16; drain16(qn); } }

        mk = __ballot(p3);
        if (p3) q[qn + __popcll(mk & below)] =
            make_float4(m23.z, m23.w, __builtin_amdgcn_rcpf(2.0f * vv.w), cc.w);
        qn += __popcll(mk);
        if (__builtin_expect(qn >= 192, 0)) { while (qn >= 16) { qn -= 16; drain16(qn); } }
    }

    while (qn >= 16) { qn -= 16; drain16(qn); }
    if (qn > 0) {                              // pad tail to a full chunk
        if (lane >= qn && lane < 16)
            q[lane] = make_float4(0.f, 0.f, 0.f, 0.f);   // cf=0: inert
        drain16(0);                            // wave-local LDS: no barrier needed
    }

    // queue regions dead from here; alias qbuf as the 4 partial 32x32 tiles
    __syncthreads();
    float (*red)[32][32] = (float (*)[32][32])qbuf;      // 16 KB alias
    #pragma unroll
    for (int r = 0; r < 16; ++r) {
        int row = (r & 3) + 8 * (r >> 2) + 4 * half;
        red[wid][row][lx] = acc[r];            // 2-way bank alias: free
    }
    __syncthreads();

    int th = threadIdx.x;
    #pragma unroll
    for (int k2 = 0; k2 < 4; ++k2) {
        int p   = th + 256 * k2;
        int row = p >> 5, col = p & 31;
        float s = red[0][row][col] + red[1][row][col]
                + red[2][row][col] + red[3][row][col];
        out[((size_t)(b * HF + ty * TS + row)) * WF + (tx * TS + col)] = s;
    }
}

extern "C" void kernel_launch(void* const* d_in, const int* in_sizes, int n_in,
                              void* d_out, int out_size, void* d_ws, size_t ws_size,
                              hipStream_t stream) {
    const float2* mean = (const float2*)d_in[0];
    const float*  var  = (const float*)d_in[1];
    const float*  conf = (const float*)d_in[2];
    float* out = (float*)d_out;
    (void)d_ws; (void)ws_size;

    pif_one<<<dim3(NTPB, B_), 256, 0, stream>>>(mean, var, conf, out);
}

// Round 13
// 19.365 us; speedup vs baseline: 1.7705x; 1.7705x over previous
//
#include <hip/hip_runtime.h>

#define B_ 4
#define J_ 8160               // 68*120 cells per batch
#define HF 544
#define WF 960
#define TS 32
#define TXN 30
#define TYN 17
#define NPX 15                // tile-PAIRS per row (64px wide each)
#define NPPB (NPX*TYN)        // 255 pairs per batch; grid = 1020 blocks = 4/CU
#define R2COEF 23.0259f       // 2*ln(1e5): exact per-cell cut (d^2 <= R2COEF*var)

typedef _Float16 half8 __attribute__((ext_vector_type(8)));
typedef float floatx16 __attribute__((ext_vector_type(16)));

// SINGLE plain dispatch (R12: cooperative launch fails graph capture; R1-R11
// fit: ~7us/node). One block per 64x32 tile-PAIR: halves the rescan (the
// binding term of R10's kernel: 266->133 MB L2, 16.6M->8.3M position tests)
// while keeping R10's independent-load scan structure exactly (R11 lesson:
// dependent predicated loads lose more to serialization than bytes save).
// Wave w scans cells [w*2048,(w+1)*2048), 2 cells/lane/iter, clamped-box test
// vs the 64x32 union, ballot-compacts records (mx,my,1/(2v),cf) into a
// per-wave LDS queue (R10-validated). Drain: 8 ey (shared) + 8 exL + 8 exR
// exps, TWO v_mfma_f32_32x32x16_f16 into per-tile accumulators (layout
// validated R3-R11). Epilogue reduces/writes the two tiles sequentially from
// the same 16KB LDS arena. (256,4): 128-VGPR budget covers the 32 acc regs.
__global__ __launch_bounds__(256, 4) void pif_pair(const float2* __restrict__ mean,
                                                   const float*  __restrict__ var,
                                                   const float*  __restrict__ conf,
                                                   float* __restrict__ out) {
    __shared__ float4 qbuf[4][256];    // per-wave queues; re-used as red[] later
    int wid  = threadIdx.x >> 6;
    int lane = threadIdx.x & 63;
    int pair = blockIdx.x;             // 0..254
    int b    = blockIdx.y;

    int pty = pair / NPX;
    int ptx = pair - pty * NPX;

    const float4* mb4 = (const float4*)(mean + (size_t)b * J_);  // 2 cells/elt
    const float2* vb2 = (const float2*)(var  + (size_t)b * J_);
    const float2* cb2 = (const float2*)(conf + (size_t)b * J_);

    float4* q = qbuf[wid];
    int qn = 0;

    float x0 = (float)(ptx * 64), y0 = (float)(pty * TS);
    float x1 = x0 + 63.f,         y1 = y0 + 31.f;   // union box of the 2 tiles
    int   lx = lane & 31, half = lane >> 5;
    float xfL = x0 + (float)lx;
    float xfR = x0 + 32.f + (float)lx;
    float yf  = y0 + (float)lx;
    const unsigned long long below = (1ull << lane) - 1ull;

    floatx16 accL = {}, accR = {};

    auto drain16 = [&](int base) {     // consumes q[base..base+15], LDS-only
        half8 af, bfl, bfr;
        #pragma unroll
        for (int i = 0; i < 8; ++i) {
            float4 e = q[base + 8 * half + i];   // uniform per half-wave: broadcast
            float dy  = yf  - e.y;
            float dxl = xfL - e.x;
            float dxr = xfR - e.x;
            af[i]  = (_Float16)__expf(-dy * dy * e.z);
            float c = e.w;
            bfl[i] = (_Float16)(c * __expf(-dxl * dxl * e.z));  // w=0 -> inert
            bfr[i] = (_Float16)(c * __expf(-dxr * dxr * e.z));
        }
        accL = __builtin_amdgcn_mfma_f32_32x32x16_f16(af, bfl, accL, 0, 0, 0);
        accR = __builtin_amdgcn_mfma_f32_32x32x16_f16(af, bfr, accR, 0, 0, 0);
    };

    int jbase = wid * 2048;                    // this wave's padded slice
    for (int s = 0; s < 16; ++s) {
        int j0 = jbase + s * 128 + 2 * lane;   // even
        bool valid = j0 < J_;                  // j0 even: valid => j0+1 valid too
        int  jh = (valid ? j0 : 0) >> 1;       // safe aligned load index

        float4 mm = mb4[jh];                   // means of the 2 cells
        float2 vv = vb2[jh];                   // their variances
        float2 cc = cb2[jh];                   // their confidences

        float cx0 = fminf(fmaxf(mm.x, x0), x1);
        float cy0 = fminf(fmaxf(mm.y, y0), y1);
        float cx1 = fminf(fmaxf(mm.z, x0), x1);
        float cy1 = fminf(fmaxf(mm.w, y0), y1);
        float dx0 = mm.x - cx0, dy0 = mm.y - cy0;
        float dx1 = mm.z - cx1, dy1 = mm.w - cy1;
        bool p0 = valid & (cc.x > 0.1f) & (dx0 * dx0 + dy0 * dy0 <= R2COEF * vv.x);
        bool p1 = valid & (cc.y > 0.1f) & (dx1 * dx1 + dy1 * dy1 <= R2COEF * vv.y);

        // compact cell 0 records (cap 256; guard keeps writes < 256 always)
        unsigned long long m0 = __ballot(p0);
        if (p0) q[qn + __popcll(m0 & below)] =
            make_float4(mm.x, mm.y, __builtin_amdgcn_rcpf(2.0f * vv.x), cc.x);
        qn += __popcll(m0);
        if (__builtin_expect(qn >= 144, 0)) {
            while (qn >= 16) { qn -= 16; drain16(qn); }
        }
        // compact cell 1 records
        unsigned long long m1 = __ballot(p1);
        if (p1) q[qn + __popcll(m1 & below)] =
            make_float4(mm.z, mm.w, __builtin_amdgcn_rcpf(2.0f * vv.y), cc.y);
        qn += __popcll(m1);
        if (__builtin_expect(qn >= 144, 0)) {
            while (qn >= 16) { qn -= 16; drain16(qn); }
        }
    }

    while (qn >= 16) { qn -= 16; drain16(qn); }
    if (qn > 0) {                              // pad tail to a full chunk
        if (lane >= qn && lane < 16)
            q[lane] = make_float4(0.f, 0.f, 0.f, 0.f);   // cf=0: inert
        drain16(0);                            // wave-local LDS: no barrier needed
    }

    // ---- Epilogue: queues dead; alias qbuf as red[4][32][32], two passes
    float (*red)[32][32] = (float (*)[32][32])qbuf;      // 16 KB alias
    int th = threadIdx.x;

    __syncthreads();
    #pragma unroll
    for (int r = 0; r < 16; ++r) {
        int row = (r & 3) + 8 * (r >> 2) + 4 * half;
        red[wid][row][lx] = accL[r];           // 2-way bank alias: free
    }
    __syncthreads();
    #pragma unroll
    for (int k = 0; k < 4; ++k) {
        int p   = th + 256 * k;
        int row = p >> 5, col = p & 31;
        float s = red[0][row][col] + red[1][row][col]
                + red[2][row][col] + red[3][row][col];
        out[((size_t)(b * HF + pty * TS + row)) * WF + (ptx * 64 + col)] = s;
    }

    __syncthreads();
    #pragma unroll
    for (int r = 0; r < 16; ++r) {
        int row = (r & 3) + 8 * (r >> 2) + 4 * half;
        red[wid][row][lx] = accR[r];
    }
    __syncthreads();
    #pragma unroll
    for (int k = 0; k < 4; ++k) {
        int p   = th + 256 * k;
        int row = p >> 5, col = p & 31;
        float s = red[0][row][col] + red[1][row][col]
                + red[2][row][col] + red[3][row][col];
        out[((size_t)(b * HF + pty * TS + row)) * WF + (ptx * 64 + 32 + col)] = s;
    }
}

extern "C" void kernel_launch(void* const* d_in, const int* in_sizes, int n_in,
                              void* d_out, int out_size, void* d_ws, size_t ws_size,
                              hipStream_t stream) {
    const float2* mean = (const float2*)d_in[0];
    const float*  var  = (const float*)d_in[1];
    const float*  conf = (const float*)d_in[2];
    float* out = (float*)d_out;
    (void)d_ws; (void)ws_size;

    pif_pair<<<dim3(NPPB, B_), 256, 0, stream>>>(mean, var, conf, out);
}